// Round 1
// baseline (190.547 us; speedup 1.0000x reference)
//
#include <hip/hip_runtime.h>

// RadialDescriptor: g[e,d] = sum_k c_table[ti,tj,d,k] * f[e,k]
//   f[e,k] = (T_k(x) + 1) * 0.5 * fc,  x = 2*(r/5-1)^2 - 1,
//   fc = 0.5*cos(pi*r/5)+0.5 for r<5 else 0.
// Memory-bound: 176 MB HBM (48 in + 128 out) -> ~28 us floor.
// Table (16 KB) staged in LDS TRANSPOSED [j][pair] so per-edge gather
// banks = p%32 (random p -> ~2-way conflicts, free). Naive [pair][j]
// layout would be 16-64-way conflicted (pair stride multiple of 32 banks).

#define KMAX 8
#define NDESC 8

__global__ __launch_bounds__(256, 4) void radial_kernel(
    const float* __restrict__ r_ij,
    const int*   __restrict__ type_i,
    const int*   __restrict__ type_j,
    const float* __restrict__ c_table,
    float*       __restrict__ out,
    int E)
{
    // lds[j*64 + p] = c_table[p*64 + j],  j = d*8+k, p = ti*8+tj
    __shared__ float lds[64 * 64];
    const int tid = threadIdx.x;
    for (int i = tid; i < 4096; i += 256) {
        int p = i >> 6, j = i & 63;
        lds[(j << 6) | p] = c_table[i];
    }
    __syncthreads();

    const int stride = gridDim.x * blockDim.x;
    for (int e = blockIdx.x * blockDim.x + tid; e < E; e += stride) {
        float r = r_ij[e];
        int   p = (type_i[e] << 3) | type_j[e];

        // fc = 0.5*cos(pi*r/5)+0.5 (r<5), pi/5 = 0.62831853...
        float fc = (r < 5.0f) ? (0.5f * __cosf(0.62831853071795864769f * r) + 0.5f)
                              : 0.0f;
        float u = r * 0.2f - 1.0f;
        float x = 2.0f * u * u - 1.0f;
        float h = 0.5f * fc;

        float f[KMAX];
        f[0] = fc;                 // (T0+1)*h = 2h = fc
        f[1] = (x + 1.0f) * h;
        float t_prev = 1.0f, t_cur = x;
        #pragma unroll
        for (int k = 2; k < KMAX; ++k) {
            float t = 2.0f * x * t_cur - t_prev;
            t_prev = t_cur; t_cur = t;
            f[k] = (t + 1.0f) * h;
        }

        float acc[NDESC];
        #pragma unroll
        for (int d = 0; d < NDESC; ++d) acc[d] = 0.0f;

        const float* colbase = lds + p;   // column p, row stride 64 floats
        #pragma unroll
        for (int d = 0; d < NDESC; ++d) {
            #pragma unroll
            for (int k = 0; k < KMAX; ++k) {
                acc[d] = fmaf(colbase[((d << 3) | k) << 6], f[k], acc[d]);
            }
        }

        float4* o = reinterpret_cast<float4*>(out + (size_t)e * 8);
        o[0] = make_float4(acc[0], acc[1], acc[2], acc[3]);
        o[1] = make_float4(acc[4], acc[5], acc[6], acc[7]);
    }
}

extern "C" void kernel_launch(void* const* d_in, const int* in_sizes, int n_in,
                              void* d_out, int out_size, void* d_ws, size_t ws_size,
                              hipStream_t stream) {
    const float* r_ij   = (const float*)d_in[0];
    const int*   type_i = (const int*)d_in[1];
    const int*   type_j = (const int*)d_in[2];
    const float* c_tab  = (const float*)d_in[3];
    float* out = (float*)d_out;
    int E = in_sizes[0];

    dim3 block(256);
    dim3 grid(2048);
    radial_kernel<<<grid, block, 0, stream>>>(r_ij, type_i, type_j, c_tab, out, E);
}